// Round 6
// baseline (147.886 us; speedup 1.0000x reference)
//
#include <hip/hip_runtime.h>

#define NN 8192
#define NE 262144
#define DIN 512
#define DH 256
#define DZ 16

typedef __attribute__((ext_vector_type(8))) short bf16x8;
typedef __attribute__((ext_vector_type(4))) float f32x4;

__device__ __forceinline__ ushort f2bf(float f) {
    uint u = __float_as_uint(f);
    uint r = (u + 0x7FFFu + ((u >> 16) & 1u)) >> 16;
    return (ushort)r;
}
__device__ __forceinline__ float bf2f(ushort h) {
    return __uint_as_float((uint)h << 16);
}

// ---------------- fused prep: cvt w1^T (blocks 0..511) + hist (blocks 512..1535) ----------------
// cursor must be zeroed (memsetAsync) before this kernel.
__global__ void k_prep_hist(const float* __restrict__ W, ushort* __restrict__ WBf,
                            const int* __restrict__ row, int* __restrict__ cnt) {
    int b = blockIdx.x;
    int t = threadIdx.x;
    if (b < 512) {
        int o = b * 256 + t;  // 256*512 elems of w1t
        int n = o >> 9, k = o & 511;
        WBf[o] = f2bf(W[(size_t)k * DH + n]);
    } else {
        int e = (b - 512) * 256 + t;
        atomicAdd(&cnt[row[e]], 1);
    }
}

// 1024 threads, 8 bins each; wave shfl scan + 16 wave-sums -> 2 barriers total
__global__ __launch_bounds__(1024) void k_scan(const int* __restrict__ cnt,
                                               int* __restrict__ row_ptr,
                                               int* __restrict__ cursor) {
    __shared__ int wsum[16];
    int t = threadIdx.x;
    int wave = t >> 6, lane = t & 63;
    int4 v0 = *(const int4*)&cnt[t * 8];
    int4 v1 = *(const int4*)&cnt[t * 8 + 4];
    int local[8] = {v0.x, v0.y, v0.z, v0.w, v1.x, v1.y, v1.z, v1.w};
    int s = 0;
#pragma unroll
    for (int j = 0; j < 8; j++) s += local[j];
    int si = s;
#pragma unroll
    for (int off = 1; off < 64; off <<= 1) {
        int u = __shfl_up(si, off);
        if (lane >= off) si += u;
    }
    if (lane == 63) wsum[wave] = si;
    __syncthreads();
    if (t < 16) {
        int w = wsum[t];
#pragma unroll
        for (int off = 1; off < 16; off <<= 1) {
            int u = __shfl_up(w, off);
            if (t >= off) w += u;
        }
        wsum[t] = w;
    }
    __syncthreads();
    int base = (wave ? wsum[wave - 1] : 0) + si - s;
#pragma unroll
    for (int j = 0; j < 8; j++) {
        row_ptr[t * 8 + j] = base;
        cursor[t * 8 + j]  = base;
        base += local[j];
    }
    if (t == 1023) row_ptr[NN] = base;
}

__global__ void k_scatter(const int* __restrict__ row, const int* __restrict__ col,
                          const float* __restrict__ ew, int* __restrict__ cursor,
                          int* __restrict__ col_s, float* __restrict__ w_s) {
    int e = blockIdx.x * blockDim.x + threadIdx.x;
    if (e < NE) {
        int r = row[e];
        int pos = atomicAdd(&cursor[r], 1);
        col_s[pos] = col[e];
        w_s[pos]   = ew[e];
    }
}

// ---------------- GEMM1 (MFMA bf16, f32 A staged+cvt inline): support1(bf16) = x @ w1 ----------------
__global__ __launch_bounds__(256) void k_gemm1_mfma(const float* __restrict__ X,
                                                    const ushort* __restrict__ B,
                                                    ushort* __restrict__ O) {
    __shared__ ushort As[64][72];
    __shared__ ushort Bs[64][72];
    int t = threadIdx.x;
    int wave = t >> 6, lane = t & 63;
    int m0 = blockIdx.x * 64, n0 = blockIdx.y * 64;
    int wm = (wave >> 1) * 32, wn = (wave & 1) * 32;
    f32x4 acc[2][2] = {};
    // A staging: thread t loads 16 consecutive f32 of row t>>2, k-chunk (t&3)*16
    int ar = t >> 2, ac = (t & 3) * 16;
    // B staging: bf16x8 units
    int r0 = t >> 3, c0 = (t & 7) * 8;
    int r1 = r0 + 32;
    int fr = lane & 15, fg = lane >> 4;
    for (int k0 = 0; k0 < DIN; k0 += 64) {
        __syncthreads();
        const float* xp = &X[(size_t)(m0 + ar) * DIN + k0 + ac];
        float4 f0 = *(const float4*)&xp[0];
        float4 f1 = *(const float4*)&xp[4];
        float4 f2 = *(const float4*)&xp[8];
        float4 f3 = *(const float4*)&xp[12];
        ushort u[16] = {f2bf(f0.x), f2bf(f0.y), f2bf(f0.z), f2bf(f0.w),
                        f2bf(f1.x), f2bf(f1.y), f2bf(f1.z), f2bf(f1.w),
                        f2bf(f2.x), f2bf(f2.y), f2bf(f2.z), f2bf(f2.w),
                        f2bf(f3.x), f2bf(f3.y), f2bf(f3.z), f2bf(f3.w)};
        *(bf16x8*)&As[ar][ac]     = *(const bf16x8*)&u[0];
        *(bf16x8*)&As[ar][ac + 8] = *(const bf16x8*)&u[8];
        *(bf16x8*)&Bs[r0][c0] = *(const bf16x8*)&B[(size_t)(n0 + r0) * DIN + k0 + c0];
        *(bf16x8*)&Bs[r1][c0] = *(const bf16x8*)&B[(size_t)(n0 + r1) * DIN + k0 + c0];
        __syncthreads();
#pragma unroll
        for (int kk = 0; kk < 2; ++kk) {
            bf16x8 af[2], bb[2];
#pragma unroll
            for (int i = 0; i < 2; ++i)
                af[i] = *(const bf16x8*)&As[wm + i * 16 + fr][kk * 32 + fg * 8];
#pragma unroll
            for (int j = 0; j < 2; ++j)
                bb[j] = *(const bf16x8*)&Bs[wn + j * 16 + fr][kk * 32 + fg * 8];
#pragma unroll
            for (int i = 0; i < 2; ++i)
#pragma unroll
                for (int j = 0; j < 2; ++j)
                    acc[i][j] = __builtin_amdgcn_mfma_f32_16x16x32_bf16(
                        af[i], bb[j], acc[i][j], 0, 0, 0);
        }
    }
#pragma unroll
    for (int i = 0; i < 2; ++i)
#pragma unroll
        for (int j = 0; j < 2; ++j)
#pragma unroll
            for (int r = 0; r < 4; ++r)
                O[(size_t)(m0 + wm + i * 16 + fg * 4 + r) * DH + n0 + wn + j * 16 + fr] =
                    f2bf(acc[i][j][r]);
}

// ---------------- fused SpMM1+GEMM2: s2 = (relu(A @ support1)) @ w2 ----------------
__global__ __launch_bounds__(256) void k_spmm1_gemm2(const ushort* __restrict__ Sbf,
                                                     const int* __restrict__ rp,
                                                     const int* __restrict__ cs,
                                                     const float* __restrict__ wsrt,
                                                     const float* __restrict__ W2,
                                                     float* __restrict__ S2) {
    __shared__ float w2s[DH * DZ];  // 16KB, [k][j]
    __shared__ float hs[2][DH];     // 2KB
    int t = threadIdx.x;
#pragma unroll
    for (int i = t; i < DH * DZ / 4; i += 256)
        ((float4*)w2s)[i] = ((const float4*)W2)[i];
    int sub = t >> 7;
    int ht = t & 127;
    int r = blockIdx.x * 2 + sub;
    int e0 = rp[r], e1 = rp[r + 1];
    float a0 = 0.f, a1 = 0.f, b0 = 0.f, b1 = 0.f;
    float c0 = 0.f, c1 = 0.f, d0 = 0.f, d1 = 0.f;
    int e = e0;
    for (; e + 3 < e1; e += 4) {
        int k0 = cs[e], k1 = cs[e + 1], k2 = cs[e + 2], k3 = cs[e + 3];
        float w0 = wsrt[e], w1 = wsrt[e + 1], w2_ = wsrt[e + 2], w3 = wsrt[e + 3];
        uint p0 = *(const uint*)&Sbf[(size_t)k0 * DH + ht * 2];
        uint p1 = *(const uint*)&Sbf[(size_t)k1 * DH + ht * 2];
        uint p2 = *(const uint*)&Sbf[(size_t)k2 * DH + ht * 2];
        uint p3 = *(const uint*)&Sbf[(size_t)k3 * DH + ht * 2];
        a0 += w0 * bf2f((ushort)p0); a1 += w0 * bf2f((ushort)(p0 >> 16));
        b0 += w1 * bf2f((ushort)p1); b1 += w1 * bf2f((ushort)(p1 >> 16));
        c0 += w2_ * bf2f((ushort)p2); c1 += w2_ * bf2f((ushort)(p2 >> 16));
        d0 += w3 * bf2f((ushort)p3); d1 += w3 * bf2f((ushort)(p3 >> 16));
    }
    for (; e < e1; ++e) {
        float w0 = wsrt[e];
        uint p0 = *(const uint*)&Sbf[(size_t)cs[e] * DH + ht * 2];
        a0 += w0 * bf2f((ushort)p0); a1 += w0 * bf2f((ushort)(p0 >> 16));
    }
    float2 o;
    o.x = fmaxf(a0 + b0 + c0 + d0, 0.f);
    o.y = fmaxf(a1 + b1 + c1 + d1, 0.f);
    *(float2*)&hs[sub][ht * 2] = o;
    __syncthreads();
    int j = (t >> 3) & 15, g = t & 7;
    float acc = 0.f;
#pragma unroll
    for (int kk = 0; kk < 32; ++kk) {
        int k = g * 32 + kk;
        acc += hs[sub][k] * w2s[k * DZ + j];
    }
    acc += __shfl_xor(acc, 1);
    acc += __shfl_xor(acc, 2);
    acc += __shfl_xor(acc, 4);
    if (g == 0) S2[(size_t)r * DZ + j] = acc;
}

// ---------------- SpMM2: z = A @ s2, epilogue -> split bf16 zhi/zlo ----------------
__global__ __launch_bounds__(256) void k_spmm2(const float* __restrict__ S2,
                                               const int* __restrict__ rp,
                                               const int* __restrict__ cs,
                                               const float* __restrict__ wsrt,
                                               ushort* __restrict__ ZHi,
                                               ushort* __restrict__ ZLo) {
    int t = threadIdx.x;
    int rl = t >> 4, c = t & 15;
    int r = blockIdx.x * 16 + rl;
    int e0 = rp[r], e1 = rp[r + 1];
    float acc = 0.f;
    for (int e = e0; e < e1; ++e) acc += wsrt[e] * S2[(size_t)cs[e] * DZ + c];
    ushort h = f2bf(acc);
    ZHi[(size_t)r * DZ + c] = h;
    ZLo[(size_t)r * DZ + c] = f2bf(acc - bf2f(h));
}

// ---------------- GEMM3 (MFMA split-bf16, K-packed): adj = z @ z.T ----------------
__global__ __launch_bounds__(256) void k_gemm3_mfma(const ushort* __restrict__ ZHi,
                                                    const ushort* __restrict__ ZLo,
                                                    float* __restrict__ O) {
    int t = threadIdx.x;
    int wave = t >> 6, lane = t & 63;
    int rb = blockIdx.y * 128 + (wave >> 1) * 64;
    int cb = blockIdx.x * 128 + (wave & 1) * 64;
    int fr = lane & 15, fg = lane >> 4;
    int ko = (fg & 1) * 8;
    const ushort* asel = (fg < 2) ? ZHi : ZLo;

    bf16x8 cpack[4], rhi[4], rlo[4];
    bf16x8 zero8 = {};
#pragma unroll
    for (int j = 0; j < 4; ++j)
        cpack[j] = *(const bf16x8*)&asel[(size_t)(cb + j * 16 + fr) * DZ + ko];
#pragma unroll
    for (int i = 0; i < 4; ++i) {
        rhi[i] = *(const bf16x8*)&ZHi[(size_t)(rb + i * 16 + fr) * DZ + ko];
        rlo[i] = (fg < 2) ? *(const bf16x8*)&ZLo[(size_t)(rb + i * 16 + fr) * DZ + ko]
                          : zero8;
    }
    f32x4 acc[4][4] = {};
#pragma unroll
    for (int i = 0; i < 4; ++i)
#pragma unroll
        for (int j = 0; j < 4; ++j) {
            acc[i][j] = __builtin_amdgcn_mfma_f32_16x16x32_bf16(cpack[j], rhi[i],
                                                                acc[i][j], 0, 0, 0);
            acc[i][j] = __builtin_amdgcn_mfma_f32_16x16x32_bf16(cpack[j], rlo[i],
                                                                acc[i][j], 0, 0, 0);
        }
#pragma unroll
    for (int i = 0; i < 4; ++i)
#pragma unroll
        for (int j = 0; j < 4; ++j)
            *(f32x4*)&O[(size_t)(rb + i * 16 + fr) * NN + cb + j * 16 + fg * 4] = acc[i][j];
}

extern "C" void kernel_launch(void* const* d_in, const int* in_sizes, int n_in,
                              void* d_out, int out_size, void* d_ws, size_t ws_size,
                              hipStream_t stream) {
    const float* x  = (const float*)d_in[0];
    const float* w1 = (const float*)d_in[1];
    const float* w2 = (const float*)d_in[2];
    const float* ew = (const float*)d_in[3];
    const int*  row = (const int*)d_in[4];
    const int*  col = (const int*)d_in[5];
    float* out = (float*)d_out;

    char* ws = (char*)d_ws;
    int*    row_ptr = (int*)ws;                        // 32772 B
    int*    cursor  = (int*)(ws + 36864);              // 32768 B
    ushort* zhi     = (ushort*)(ws + 73728);           // 256KB
    ushort* zlo     = (ushort*)(ws + 73728 + 262144);  // 256KB

    char* ob = (char*)d_out;
    ushort* support1 = (ushort*)ob;                       // 4MB bf16
    float*  s2       = (float*)(ob + 16u * 1024 * 1024);  // 512KB
    int*    col_s    = (int*)(ob + 17u * 1024 * 1024);    // 1MB
    float*  w_s      = (float*)(ob + 18u * 1024 * 1024);  // 1MB
    ushort* w1tbf    = (ushort*)(ob + 36u * 1024 * 1024); // 256KB

    hipMemsetAsync(cursor, 0, NN * sizeof(int), stream);
    k_prep_hist<<<1536, 256, 0, stream>>>(w1, w1tbf, row, cursor);
    k_scan<<<1, 1024, 0, stream>>>(cursor, row_ptr, cursor);
    k_scatter<<<NE / 256, 256, 0, stream>>>(row, col, ew, cursor, col_s, w_s);

    k_gemm1_mfma<<<dim3(NN / 64, DH / 64), 256, 0, stream>>>(x, w1tbf, support1);
    k_spmm1_gemm2<<<NN / 2, 256, 0, stream>>>(support1, row_ptr, col_s, w_s, w2, s2);

    k_spmm2<<<NN / 16, 256, 0, stream>>>(s2, row_ptr, col_s, w_s, zhi, zlo);

    k_gemm3_mfma<<<dim3(NN / 128, NN / 128), 256, 0, stream>>>(zhi, zlo, out);
}